// Round 1
// baseline (68.527 us; speedup 1.0000x reference)
//
#include <hip/hip_runtime.h>
#include <math.h>

// Problem constants (from reference setup_inputs)
#define BSZ   16     // batch
#define NCAPS 1152   // num primary caps
#define DP    8      // dim primary caps
#define MCAPS 10     // num digit caps
#define DD    16     // dim digit caps

// ---------------------------------------------------------------------------
// Single fused kernel, no workspace, one launch.
//
// Math (reference collapses): softmax over a size-1 axis == 1, so
//   out[b,m,:] = squash( sum_n (1 + Bp[m,n]) * (W[m,n,:,:] @ u[b,n,:]) )
//
// One block per (b,m) pair: the n=1152 reduction AND the d=16 squash norm are
// both block-local -> no cross-block reduction, no workspace, no 2nd launch.
//
// Thread layout: 256 threads = (ng in 0..15) x (d in 0..15), lane n-mapping
// n = i*16 + ng so that:
//   - per wave (4 ng x 16 d) the W reads are one fully-contiguous 2 KB span
//   - the four u_t ds_read_b128 addrs land on banks {0-7,8-15,16-23,24-31}
//     (conflict-free; 16-lane broadcast per address)
// W[m] (590 KB) is streamed from global exactly once per block (each element
// used once per block -> no LDS staging for W). u[b] (36 KB) + Bp[m] (4.5 KB)
// are staged in LDS since they're reused 16x within the block.
// ---------------------------------------------------------------------------
__global__ __launch_bounds__(256) void digitcaps_fused(
    const float* __restrict__ u,    // [BSZ][NCAPS][DP]
    const float* __restrict__ W,    // [MCAPS][NCAPS][DD][DP]
    const float* __restrict__ Bp,   // [MCAPS][NCAPS]  (B_prior squeezed)
    float* __restrict__ out)        // [BSZ][MCAPS][DD]
{
    __shared__ float u_t[NCAPS][DP];   // 36 KB
    __shared__ float bp_t[NCAPS];      // 4.5 KB
    __shared__ float red[16][DD];      // ng-partials for the final reduce

    const int t = threadIdx.x;

    // XCD-locality mapping: round-robin dispatch sends block -> XCD (blk & 7).
    // Give each XCD a contiguous run of 20 (m,b) pairs so its ~2 distinct m
    // values keep W[m] (590 KB each) resident in that XCD's private L2.
    // Bijective for 160 blocks; perf-only heuristic (correct regardless).
    const int p = (blockIdx.x & 7) * 20 + (blockIdx.x >> 3);  // 0..159
    const int m = p >> 4;   // 0..9
    const int b = p & 15;   // 0..15

    // --- stage u[b]: 1152*8 floats = 2304 float4 (9 per thread, coalesced) ---
    {
        const float4* ug = (const float4*)(u + (size_t)b * NCAPS * DP);
        float4* ul = (float4*)&u_t[0][0];
#pragma unroll
        for (int i = 0; i < 9; ++i) ul[t + 256 * i] = ug[t + 256 * i];

        // --- stage Bp[m]: 1152 floats = 288 float4 ---
        const float4* bg = (const float4*)(Bp + (size_t)m * NCAPS);
        float4* bl = (float4*)bp_t;
        bl[t] = bg[t];
        if (t < 32) bl[256 + t] = bg[256 + t];
    }
    __syncthreads();

    const int d  = t & 15;   // output dim this thread accumulates
    const int ng = t >> 4;   // n-interleave group 0..15

    const float* wp = W + (size_t)m * NCAPS * DD * DP
                        + (size_t)ng * DD * DP
                        + (size_t)d * DP;

    float acc = 0.0f;
#pragma unroll 8
    for (int i = 0; i < NCAPS / 16; ++i) {           // 72 iterations
        const int n = i * 16 + ng;
        const float4 w0 = *(const float4*)(wp + (size_t)i * 16 * DD * DP);
        const float4 w1 = *(const float4*)(wp + (size_t)i * 16 * DD * DP + 4);
        const float4 u0 = *(const float4*)&u_t[n][0];
        const float4 u1 = *(const float4*)&u_t[n][4];
        float dot = w0.x * u0.x + w0.y * u0.y + w0.z * u0.z + w0.w * u0.w
                  + w1.x * u1.x + w1.y * u1.y + w1.z * u1.z + w1.w * u1.w;
        acc = fmaf(1.0f + bp_t[n], dot, acc);        // CB = 1 + B_prior
    }

    // --- block-local reduce over the 16 ng groups, then squash over d ---
    red[ng][d] = acc;
    __syncthreads();

    if (t < DD) {                                    // lanes 0..15 of wave 0
        float s = 0.0f;
#pragma unroll
        for (int g = 0; g < 16; ++g) s += red[g][t]; // conflict-free rows

        float ss = s * s;                            // ||S||^2 via 16-lane butterfly
#pragma unroll
        for (int w = 1; w < 16; w <<= 1) ss += __shfl_xor(ss, w, 16);

        float norm  = sqrtf(ss);
        float scale = (1.0f - expf(-norm)) / (norm + 1e-7f);
        out[(b * MCAPS + m) * DD + t] = scale * s;
    }
}

extern "C" void kernel_launch(void* const* d_in, const int* in_sizes, int n_in,
                              void* d_out, int out_size, void* d_ws, size_t ws_size,
                              hipStream_t stream) {
    const float* u  = (const float*)d_in[0];  // primary_caps [16,1152,8]
    const float* W  = (const float*)d_in[1];  // W            [10,1152,16,8]
    const float* Bp = (const float*)d_in[2];  // B_prior      [10,1,1152]
    float* out = (float*)d_out;               // [16,10,16]
    (void)d_ws; (void)ws_size;                // workspace intentionally unused

    digitcaps_fused<<<dim3(BSZ * MCAPS), dim3(256), 0, stream>>>(u, W, Bp, out);
}

// Round 3
// 63.993 us; speedup vs baseline: 1.0708x; 1.0708x over previous
//
#include <hip/hip_runtime.h>
#include <math.h>

// Problem constants (from reference setup_inputs)
#define BSZ   16     // batch
#define NCAPS 1152   // num primary caps
#define DP    8      // dim primary caps
#define MCAPS 10     // num digit caps
#define DD    16     // dim digit caps

#define NC    16                 // n per block in kernel 1
#define NCH   (NCAPS / NC)       // 72 chunks per m

// ---------------------------------------------------------------------------
// Math (reference collapses): softmax over a size-1 axis == 1, so
//   out[b,m,:] = squash( sum_n (1 + Bp[m,n]) * (W[m,n,:,:] @ u[b,n,:]) )
//
// Harness poisons the full 256 MiB workspace every iteration regardless of
// use (measured R1) -> using ws is free. Two lean kernels:
//
// Kernel 1: one block per (m, 16-n chunk) = 720 blocks. Thread (ng,d) owns
// W[m][n0+ng][d][:] IN REGISTERS (W read exactly once from HBM, coalesced
// 2 KB/wave), with (1+Bp) folded into the w registers. u chunk for ALL 16 b
// staged once in LDS (8 KB). Inner loop over b: 2 broadcast ds_read_b128 +
// 8 FMA each -> only 32 ds_reads/thread (vs 96 in the round-0 kernel).
// n-sum happens via the ng dimension: __shfl_xor(16|32) reduces 4 ng per
// wave, 4-wave LDS tile finishes it.
// ---------------------------------------------------------------------------
__global__ __launch_bounds__(256) void digitcaps_partial(
    const float* __restrict__ u,    // [BSZ][NCAPS][DP]
    const float* __restrict__ W,    // [MCAPS][NCAPS][DD][DP]
    const float* __restrict__ Bp,   // [MCAPS][NCAPS]
    float* __restrict__ part)       // [MCAPS][BSZ][NCH][DD]
{
    __shared__ float u_t[BSZ][NC][DP];   // 8 KB
    __shared__ float red[4][BSZ][DD];    // 4 KB (per-wave ng-partials)

    const int t  = threadIdx.x;
    const int m  = blockIdx.x / NCH;
    const int c  = blockIdx.x % NCH;
    const int n0 = c * NC;

    const int d  = t & 15;   // 0..15
    const int ng = t >> 4;   // 0..15, n = n0 + ng

    // --- W row for this (n,d) straight to registers; coalesced 2 KB/wave ---
    const float* wp = W + (((size_t)(m * NCAPS + n0 + ng)) * DD + d) * DP;
    float4 w0 = *(const float4*)(wp);
    float4 w1 = *(const float4*)(wp + 4);

    // --- stage u chunk for all b: 16 b x 128 contiguous floats each ---
    {
        float4* ul = (float4*)&u_t[0][0][0];
#pragma unroll
        for (int i = 0; i < 2; ++i) {
            int idx = t + 256 * i;           // 0..511
            int b   = idx >> 5;              // /32 float4 per b
            int off = idx & 31;
            ul[idx] = ((const float4*)(u + ((size_t)b * NCAPS + n0) * DP))[off];
        }
    }

    // fold (1 + B_prior) into the w registers (per-thread n is fixed)
    const float bpv = 1.0f + Bp[m * NCAPS + n0 + ng];
    w0.x *= bpv; w0.y *= bpv; w0.z *= bpv; w0.w *= bpv;
    w1.x *= bpv; w1.y *= bpv; w1.z *= bpv; w1.w *= bpv;

    __syncthreads();

    // --- acc[b] = <w', u[b,n,:]> ; broadcast LDS reads (16 lanes/addr) ---
    float acc[BSZ];
#pragma unroll
    for (int b = 0; b < BSZ; ++b) {
        const float4 u0 = *(const float4*)&u_t[b][ng][0];
        const float4 u1 = *(const float4*)&u_t[b][ng][4];
        acc[b] = w0.x * u0.x + w0.y * u0.y + w0.z * u0.z + w0.w * u0.w
               + w1.x * u1.x + w1.y * u1.y + w1.z * u1.z + w1.w * u1.w;
    }

    // --- reduce over ng: 4 ng per wave via shfl, then 4 waves via LDS ---
    const int wv   = t >> 6;        // wave id 0..3
    const int lane = t & 63;
#pragma unroll
    for (int b = 0; b < BSZ; ++b) {
        float v = acc[b];
        v += __shfl_xor(v, 16);
        v += __shfl_xor(v, 32);
        if (lane < 16) red[wv][b][lane] = v;
    }
    __syncthreads();

    const int b2 = t >> 4;          // reuse 256 threads as (b,d)
    float s = red[0][b2][d] + red[1][b2][d] + red[2][b2][d] + red[3][b2][d];

    // part[m][b][c][d]: makes kernel 2's read one contiguous run per (b,m)
    part[(((size_t)(m * BSZ + b2)) * NCH + c) * DD + d] = s;
}

// ---------------------------------------------------------------------------
// Kernel 2: one wave per (b,m). Reads part[m][b][0..71][0..15] = 4.6 KB
// fully contiguous (lane l, iter i reads base + i*64 + l). shfl-reduce the
// 4 chunk-groups, then 16-lane butterfly for the squash norm.
// ---------------------------------------------------------------------------
__global__ __launch_bounds__(64) void digitcaps_reduce_squash(
    const float* __restrict__ part, // [MCAPS][BSZ][NCH][DD]
    float* __restrict__ out)        // [BSZ][MCAPS][DD]
{
    const int bm = blockIdx.x;            // 0..159
    const int m  = bm % MCAPS;
    const int bb = bm / MCAPS;

    const int l = threadIdx.x;            // 0..63
    const float* p = part + ((size_t)(m * BSZ + bb)) * NCH * DD;

    float s = 0.0f;
#pragma unroll
    for (int i = 0; i < (NCH * DD) / 64; ++i) {   // 18 fully-coalesced loads
        s += p[i * 64 + l];
    }
    // lanes differing in bits 4,5 hold other chunk-quarters of same d
    s += __shfl_xor(s, 16);
    s += __shfl_xor(s, 32);

    // squash: ||S||^2 via 16-lane butterfly over d
    float ss = s * s;
#pragma unroll
    for (int w = 1; w < 16; w <<= 1) ss += __shfl_xor(ss, w, 16);

    if (l < DD) {
        float norm  = sqrtf(ss);
        float scale = (1.0f - expf(-norm)) / (norm + 1e-7f);
        out[(bb * MCAPS + m) * DD + l] = scale * s;
    }
}

extern "C" void kernel_launch(void* const* d_in, const int* in_sizes, int n_in,
                              void* d_out, int out_size, void* d_ws, size_t ws_size,
                              hipStream_t stream) {
    const float* u  = (const float*)d_in[0];  // primary_caps [16,1152,8]
    const float* W  = (const float*)d_in[1];  // W            [10,1152,16,8]
    const float* Bp = (const float*)d_in[2];  // B_prior      [10,1,1152]
    float* out  = (float*)d_out;              // [16,10,16]
    float* part = (float*)d_ws;               // 10*16*72*16 floats = 737 KB

    digitcaps_partial<<<dim3(MCAPS * NCH), dim3(256), 0, stream>>>(u, W, Bp, part);
    digitcaps_reduce_squash<<<dim3(BSZ * MCAPS), dim3(64), 0, stream>>>(part, out);
}